// Round 9
// baseline (116.136 us; speedup 1.0000x reference)
//
#include <hip/hip_runtime.h>
#include <math.h>

// Problem constants
// B=16, O=24, V=2, P0=32, P1=64, P2=64, R=3, C=16, UI=1, BI=2
// NUM_IN = 288, P = 552 perms (p = a*23 + j, bb = j + (j>=a), aadj = a - (a>bb))
// in_tensor per (b,p): [nullary(32)@i0 | unary[a](64)@i32 | unary[bb](64)@i96 |
//                       binary[a][j](64)@i160 | binary[bb][aadj](64)@i224]
// Factorization: conj(b,p,r,c) = T0(b)·T1(b,a)·T2(b,bb)·T3(b,a,j)·T4(b,bb,aadj)
// out: [nullary_out(16) | unary_out(16*24) | binary_out(16*24*23)]

__device__ __forceinline__ float sigm(float x) { return 1.0f / (1.0f + expf(-x)); }

// ---------------- Kernel 1: softmax prep ----------------
// and_kernel (3,16,288,3) -> dke2[i 288][c 16][6] = {d0,e0,d1,e1,d2,e2}
// term: x*s0 + (1-x)*s1 + s2 = fma(x, s0-s1, s1+s2) = fma(x, d, e)
__global__ __launch_bounds__(256) void prep_kernel(const float* __restrict__ ak,
                                                   const float* __restrict__ temp,
                                                   float* __restrict__ dke2) {
    int idx = blockIdx.x * 256 + threadIdx.x;   // (r,c,i) over 3*16*288
    if (idx >= 3 * 16 * 288) return;
    int i = idx % 288;
    int c = (idx / 288) % 16;
    int r = idx / (16 * 288);
    float invT = 1.0f / temp[0];
    const float* p = ak + (size_t)idx * 3;
    float a0 = p[0] * invT, a1 = p[1] * invT, a2 = p[2] * invT;
    float mx = fmaxf(a0, fmaxf(a1, a2));
    float e0 = expf(a0 - mx), e1 = expf(a1 - mx), e2 = expf(a2 - mx);
    float inv = 1.0f / (e0 + e1 + e2);
    float s0 = e0 * inv, s1 = e1 * inv, s2 = e2 * inv;
    float* q = dke2 + ((size_t)i * 16 + c) * 6 + 2 * r;
    q[0] = s0 - s1;   // d
    q[1] = s1 + s2;   // e
}

// ---------------- Kernel 2: binary segment products (the hot one) ----------------
// grid: 16*24 = 384 blocks (b, a). block: 256 threads = pj(16) x c(16).
// Thread computes, for entries j1=pj and j2=pj+16 (j<23 valid), the products
//   T3[b,a,j,r,c] = prod_{il<64} fma(binary[b,a,j,il], d3, e3)
//   T4[b,a,j,r,c] = prod_{il<64} fma(binary[b,a,j,il], d4, e4)
// Coeffs (seg3: i=160+il, seg4: i=224+il) staged in LDS; x staged in LDS.
// Inner loop is pure LDS+VALU -> no global-latency exposure.
#define XJST 68
__global__ __launch_bounds__(256) void segprod_kernel(const float* __restrict__ binary,
                                                      const float* __restrict__ dke2,
                                                      float* __restrict__ t3,
                                                      float* __restrict__ t4) {
    __shared__ float xj[24 * XJST];     // 6.5 KB (rows padded to 68 floats)
    __shared__ float ck3[64 * 16 * 6];  // 24.6 KB
    __shared__ float ck4[64 * 16 * 6];  // 24.6 KB

    const int tid = threadIdx.x;
    const int b = blockIdx.x / 24;
    const int a = blockIdx.x % 24;

    // stage x: 24 rows (23 real + pad=dup of 22), 16 float4 each
    for (int idx = tid; idx < 24 * 16; idx += 256) {
        int j = idx >> 4, q = idx & 15;
        int je = j < 23 ? j : 22;
        float4 v = *(const float4*)(binary + (((size_t)b * 24 + a) * 23 + je) * 64 + q * 4);
        *(float4*)&xj[j * XJST + q * 4] = v;
    }
    // stage coeffs: 1536 float4 per segment
    for (int idx = tid; idx < 1536; idx += 256) {
        *(float4*)&ck3[idx * 4] = *(const float4*)(dke2 + 160 * 96 + idx * 4);
        *(float4*)&ck4[idx * 4] = *(const float4*)(dke2 + 224 * 96 + idx * 4);
    }
    __syncthreads();

    const int pj = tid >> 4;
    const int c  = tid & 15;
    const int j1 = pj;
    const int j2 = pj + 16;
    const int j2e = j2 < 24 ? j2 : 23;

    float acc[2][2][3];
#pragma unroll
    for (int j = 0; j < 2; ++j)
#pragma unroll
        for (int s = 0; s < 2; ++s)
#pragma unroll
            for (int r = 0; r < 3; ++r) acc[j][s][r] = 1.0f;

    for (int i0 = 0; i0 < 16; ++i0) {
        float4 xa = *(const float4*)&xj[j1 * XJST + i0 * 4];
        float4 xb = *(const float4*)&xj[j2e * XJST + i0 * 4];
        const float* xap = (const float*)&xa;
        const float* xbp = (const float*)&xb;
#pragma unroll
        for (int s = 0; s < 4; ++s) {
            const int i = i0 * 4 + s;
            const float2* k3 = (const float2*)&ck3[(i * 16 + c) * 6];
            const float2* k4 = (const float2*)&ck4[(i * 16 + c) * 6];
            float2 d30 = k3[0], d31 = k3[1], d32 = k3[2];
            float2 d40 = k4[0], d41 = k4[1], d42 = k4[2];
            float x1 = xap[s], x2 = xbp[s];
            acc[0][0][0] *= fmaf(x1, d30.x, d30.y);
            acc[0][0][1] *= fmaf(x1, d31.x, d31.y);
            acc[0][0][2] *= fmaf(x1, d32.x, d32.y);
            acc[0][1][0] *= fmaf(x1, d40.x, d40.y);
            acc[0][1][1] *= fmaf(x1, d41.x, d41.y);
            acc[0][1][2] *= fmaf(x1, d42.x, d42.y);
            acc[1][0][0] *= fmaf(x2, d30.x, d30.y);
            acc[1][0][1] *= fmaf(x2, d31.x, d31.y);
            acc[1][0][2] *= fmaf(x2, d32.x, d32.y);
            acc[1][1][0] *= fmaf(x2, d40.x, d40.y);
            acc[1][1][1] *= fmaf(x2, d41.x, d41.y);
            acc[1][1][2] *= fmaf(x2, d42.x, d42.y);
        }
    }

    // store: t3/t4 layout [b][a][j][r*16+c]
    {
        size_t base1 = (((size_t)b * 24 + a) * 23 + j1) * 48 + c;
#pragma unroll
        for (int r = 0; r < 3; ++r) {
            t3[base1 + r * 16] = acc[0][0][r];
            t4[base1 + r * 16] = acc[0][1][r];
        }
        if (j2 < 23) {
            size_t base2 = (((size_t)b * 24 + a) * 23 + j2) * 48 + c;
#pragma unroll
            for (int r = 0; r < 3; ++r) {
                t3[base2 + r * 16] = acc[1][0][r];
                t4[base2 + r * 16] = acc[1][1][r];
            }
        }
    }
}

// ---------------- Kernel 3: combine + all reductions ----------------
// grid: 16 blocks (b). block: 384 threads = a(24) x c(16).
// Thread (a,c): computes T0 (redundant per c), T1[a], T2[a] (to LDS), then loops
// the 23 perms of its a: conj[r] = T0*T1*T2[bb]*T3[a,j]*T4[bb,aadj]; emits
// binary out (c-shuffle), unary out (c-shuffle), nullary partial (LDS + wave 0).
__global__ __launch_bounds__(384) void combine_kernel(const float* __restrict__ nullary,
                                                      const float* __restrict__ unary,
                                                      const float* __restrict__ dke2,
                                                      const float* __restrict__ t3,
                                                      const float* __restrict__ t4,
                                                      const float* __restrict__ orK,
                                                      const float* __restrict__ temp,
                                                      float* __restrict__ out) {
    __shared__ float t2sh[24][48];
    __shared__ float nsh[24][16];

    const int tid = threadIdx.x;
    const int b = blockIdx.x;
    const int a = tid >> 4;
    const int c = tid & 15;
    const float T = temp[0];

    float T0[3] = {1.0f, 1.0f, 1.0f};
    for (int i = 0; i < 32; ++i) {
        float x = nullary[b * 32 + i];
        const float2* k = (const float2*)(dke2 + ((size_t)i * 16 + c) * 6);
        float2 k0 = k[0], k1 = k[1], k2 = k[2];
        T0[0] *= fmaf(x, k0.x, k0.y);
        T0[1] *= fmaf(x, k1.x, k1.y);
        T0[2] *= fmaf(x, k2.x, k2.y);
    }

    float T1[3] = {1.0f, 1.0f, 1.0f};
    float T2l[3] = {1.0f, 1.0f, 1.0f};
    const float* urow = unary + ((size_t)b * 24 + a) * 64;
    for (int i = 0; i < 64; ++i) {
        float x = urow[i];
        const float2* k1p = (const float2*)(dke2 + ((size_t)(32 + i) * 16 + c) * 6);
        const float2* k2p = (const float2*)(dke2 + ((size_t)(96 + i) * 16 + c) * 6);
        float2 p0 = k1p[0], p1 = k1p[1], p2 = k1p[2];
        float2 q0 = k2p[0], q1 = k2p[1], q2 = k2p[2];
        T1[0] *= fmaf(x, p0.x, p0.y);
        T1[1] *= fmaf(x, p1.x, p1.y);
        T1[2] *= fmaf(x, p2.x, p2.y);
        T2l[0] *= fmaf(x, q0.x, q0.y);
        T2l[1] *= fmaf(x, q1.x, q1.y);
        T2l[2] *= fmaf(x, q2.x, q2.y);
    }
#pragma unroll
    for (int r = 0; r < 3; ++r) t2sh[a][r * 16 + c] = T2l[r];
    __syncthreads();

    const float ok2 = sigm(orK[32 + c] / T);
    float u1 = 1.0f, u0 = 1.0f;

    for (int j = 0; j < 23; ++j) {
        int bb = j + (j >= a ? 1 : 0);
        int aadj = (a > bb) ? (a - 1) : a;
        size_t base3 = (((size_t)b * 24 + a) * 23 + j) * 48 + c;
        size_t base4 = (((size_t)b * 24 + bb) * 23 + aadj) * 48 + c;
        float conj0 = T0[0] * T1[0] * t2sh[bb][c]      * t3[base3]      * t4[base4];
        float conj1 = T0[1] * T1[1] * t2sh[bb][16 + c] * t3[base3 + 16] * t4[base4 + 16];
        float conj2 = T0[2] * T1[2] * t2sh[bb][32 + c] * t3[base3 + 32] * t4[base4 + 32];
        // binary out
        float w = 1.0f - conj2 * ok2;
#pragma unroll
        for (int off = 1; off < 16; off <<= 1) w *= __shfl_xor(w, off, 16);
        if (c == 0) out[400 + ((size_t)b * 24 + a) * 23 + j] = 1.0f - w;
        u1 *= (1.0f - conj1);
        u0 *= (1.0f - conj0);
    }

    // unary out
    {
        float ok1 = sigm(orK[16 + c] / T);
        float w = 1.0f - (1.0f - u1) * ok1;
#pragma unroll
        for (int off = 1; off < 16; off <<= 1) w *= __shfl_xor(w, off, 16);
        if (c == 0) out[16 + (size_t)b * 24 + a] = 1.0f - w;
    }

    // nullary
    nsh[a][c] = u0;
    __syncthreads();
    if (tid < 16) {
        int cc = tid;
        float p = 1.0f;
#pragma unroll
        for (int aa = 0; aa < 24; ++aa) p *= nsh[aa][cc];
        float ok0 = sigm(orK[cc] / T);
        float w = 1.0f - (1.0f - p) * ok0;
#pragma unroll
        for (int off = 1; off < 16; off <<= 1) w *= __shfl_xor(w, off, 16);
        if (cc == 0) out[b] = 1.0f - w;
    }
}

extern "C" void kernel_launch(void* const* d_in, const int* in_sizes, int n_in,
                              void* d_out, int out_size, void* d_ws, size_t ws_size,
                              hipStream_t stream) {
    const float* nullary = (const float*)d_in[0];   // (16,32)
    const float* unary   = (const float*)d_in[1];   // (16,24,64)
    const float* binary  = (const float*)d_in[2];   // (16,24,23,64)
    const float* ak      = (const float*)d_in[3];   // (3,16,288,3)
    const float* orK     = (const float*)d_in[4];   // (3,16)
    const float* temp    = (const float*)d_in[5];   // scalar

    float* out  = (float*)d_out;                    // 16 + 384 + 8832 floats
    float* dke2 = (float*)d_ws;                     // 288*16*6 = 27648 floats
    float* t3   = dke2 + 27648;                     // 16*24*23*48 = 423936
    float* t4   = t3 + 423936;                      // 423936

    prep_kernel<<<54, 256, 0, stream>>>(ak, temp, dke2);
    segprod_kernel<<<16 * 24, 256, 0, stream>>>(binary, dke2, t3, t4);
    combine_kernel<<<16, 384, 0, stream>>>(nullary, unary, dke2, t3, t4, orK, temp, out);
}

// Round 10
// 90.376 us; speedup vs baseline: 1.2850x; 1.2850x over previous
//
#include <hip/hip_runtime.h>
#include <math.h>

// Problem constants
// B=16, O=24, V=2, P0=32, P1=64, P2=64, R=3, C=16, UI=1, BI=2
// NUM_IN = 288, P = 552 perms (p = a*23 + j, bb = j + (j>=a), aadj = a - (a>bb))
// in_tensor per (b,p): [nullary(32)@i0 | unary[a](64)@i32 | unary[bb](64)@i96 |
//                       binary[a][j](64)@i160 | binary[bb][aadj](64)@i224]
// Factorization: conj(b,p,r,c) = U1(b,a)·U2(b,bb)·T3(b,a,j)·T4(b,bb,aadj)
//   with U1 = T0·T1 (nullary + unary[a] segments), U2 = unary[bb] segment.
// out: [nullary_out(16) | unary_out(16*24) | binary_out(16*24*23)]

__device__ __forceinline__ float sigm(float x) { return 1.0f / (1.0f + expf(-x)); }

// ---------------- Kernel 1: softmax prep ----------------
// and_kernel (3,16,288,3) -> dke2[i 288][c 16][6] = {d0,e0,d1,e1,d2,e2}
// term: x*s0 + (1-x)*s1 + s2 = fma(x, s0-s1, s1+s2) = fma(x, d, e)
__global__ __launch_bounds__(256) void prep_kernel(const float* __restrict__ ak,
                                                   const float* __restrict__ temp,
                                                   float* __restrict__ dke2) {
    int idx = blockIdx.x * 256 + threadIdx.x;   // (r,c,i) over 3*16*288
    if (idx >= 3 * 16 * 288) return;
    int i = idx % 288;
    int c = (idx / 288) % 16;
    int r = idx / (16 * 288);
    float invT = 1.0f / temp[0];
    const float* p = ak + (size_t)idx * 3;
    float a0 = p[0] * invT, a1 = p[1] * invT, a2 = p[2] * invT;
    float mx = fmaxf(a0, fmaxf(a1, a2));
    float e0 = expf(a0 - mx), e1 = expf(a1 - mx), e2 = expf(a2 - mx);
    float inv = 1.0f / (e0 + e1 + e2);
    float s0 = e0 * inv, s1 = e1 * inv, s2 = e2 * inv;
    float* q = dke2 + ((size_t)i * 16 + c) * 6 + 2 * r;
    q[0] = s0 - s1;   // d
    q[1] = s1 + s2;   // e
}

// ---------------- Kernel 2: binary segment products (the hot one) ----------------
// grid: 16*24 = 384 blocks (b, a). block: 256 threads = pj(16) x c(16).
// T3[b,a,j,r,c] = prod_{il<64} fma(binary[b,a,j,il], d(160+il), e(160+il))
// T4[b,a,j,r,c] = prod_{il<64} fma(binary[b,a,j,il], d(224+il), e(224+il))
// Coeffs + x staged in LDS; inner loop pure LDS+VALU.
#define XJST 68
__global__ __launch_bounds__(256) void segprod_kernel(const float* __restrict__ binary,
                                                      const float* __restrict__ dke2,
                                                      float* __restrict__ t3,
                                                      float* __restrict__ t4) {
    __shared__ float xj[24 * XJST];     // 6.5 KB
    __shared__ float ck3[64 * 16 * 6];  // 24.6 KB
    __shared__ float ck4[64 * 16 * 6];  // 24.6 KB

    const int tid = threadIdx.x;
    const int b = blockIdx.x / 24;
    const int a = blockIdx.x % 24;

    for (int idx = tid; idx < 24 * 16; idx += 256) {
        int j = idx >> 4, q = idx & 15;
        int je = j < 23 ? j : 22;
        float4 v = *(const float4*)(binary + (((size_t)b * 24 + a) * 23 + je) * 64 + q * 4);
        *(float4*)&xj[j * XJST + q * 4] = v;
    }
    for (int idx = tid; idx < 1536; idx += 256) {
        *(float4*)&ck3[idx * 4] = *(const float4*)(dke2 + 160 * 96 + idx * 4);
        *(float4*)&ck4[idx * 4] = *(const float4*)(dke2 + 224 * 96 + idx * 4);
    }
    __syncthreads();

    const int pj = tid >> 4;
    const int c  = tid & 15;
    const int j1 = pj;
    const int j2 = pj + 16;
    const int j2e = j2 < 24 ? j2 : 23;

    float acc[2][2][3];
#pragma unroll
    for (int j = 0; j < 2; ++j)
#pragma unroll
        for (int s = 0; s < 2; ++s)
#pragma unroll
            for (int r = 0; r < 3; ++r) acc[j][s][r] = 1.0f;

    for (int i0 = 0; i0 < 16; ++i0) {
        float4 xa = *(const float4*)&xj[j1 * XJST + i0 * 4];
        float4 xb = *(const float4*)&xj[j2e * XJST + i0 * 4];
        const float* xap = (const float*)&xa;
        const float* xbp = (const float*)&xb;
#pragma unroll
        for (int s = 0; s < 4; ++s) {
            const int i = i0 * 4 + s;
            const float2* k3 = (const float2*)&ck3[(i * 16 + c) * 6];
            const float2* k4 = (const float2*)&ck4[(i * 16 + c) * 6];
            float2 d30 = k3[0], d31 = k3[1], d32 = k3[2];
            float2 d40 = k4[0], d41 = k4[1], d42 = k4[2];
            float x1 = xap[s], x2 = xbp[s];
            acc[0][0][0] *= fmaf(x1, d30.x, d30.y);
            acc[0][0][1] *= fmaf(x1, d31.x, d31.y);
            acc[0][0][2] *= fmaf(x1, d32.x, d32.y);
            acc[0][1][0] *= fmaf(x1, d40.x, d40.y);
            acc[0][1][1] *= fmaf(x1, d41.x, d41.y);
            acc[0][1][2] *= fmaf(x1, d42.x, d42.y);
            acc[1][0][0] *= fmaf(x2, d30.x, d30.y);
            acc[1][0][1] *= fmaf(x2, d31.x, d31.y);
            acc[1][0][2] *= fmaf(x2, d32.x, d32.y);
            acc[1][1][0] *= fmaf(x2, d40.x, d40.y);
            acc[1][1][1] *= fmaf(x2, d41.x, d41.y);
            acc[1][1][2] *= fmaf(x2, d42.x, d42.y);
        }
    }

    {
        size_t base1 = (((size_t)b * 24 + a) * 23 + j1) * 48 + c;
#pragma unroll
        for (int r = 0; r < 3; ++r) {
            t3[base1 + r * 16] = acc[0][0][r];
            t4[base1 + r * 16] = acc[0][1][r];
        }
        if (j2 < 23) {
            size_t base2 = (((size_t)b * 24 + a) * 23 + j2) * 48 + c;
#pragma unroll
            for (int r = 0; r < 3; ++r) {
                t3[base2 + r * 16] = acc[1][0][r];
                t4[base2 + r * 16] = acc[1][1][r];
            }
        }
    }
}

// ---------------- Kernel 3: unary-segment products ----------------
// grid: 384 blocks (b*24+a). block: 128 threads, two waves:
//   wave 0 (tid<48):       U1[ba][rc] = prod_{i<32} null-term * prod_{i<64} unary[a]-term(seg1)
//   wave 1 (tid-64 < 48):  U2[ba][rc] = prod_{i<64} unary[a]-term(seg2)
__global__ __launch_bounds__(128) void useg_kernel(const float* __restrict__ nullary,
                                                   const float* __restrict__ unary,
                                                   const float* __restrict__ dke2,
                                                   float* __restrict__ U1,
                                                   float* __restrict__ U2) {
    const int tid = threadIdx.x;
    const int ba = blockIdx.x;
    const int b = ba / 24;
    const int half = tid >> 6;
    const int rc = tid & 63;
    if (rc >= 48) return;
    const int c = rc & 15, r = rc >> 4;

    float acc = 1.0f;
    const float* urow = unary + (size_t)ba * 64;
    if (half == 0) {
        const float* nrow = nullary + b * 32;
#pragma unroll 8
        for (int i = 0; i < 32; ++i) {
            const float* k = dke2 + ((size_t)i * 16 + c) * 6 + 2 * r;
            acc *= fmaf(nrow[i], k[0], k[1]);
        }
#pragma unroll 8
        for (int i = 0; i < 64; ++i) {
            const float* k = dke2 + ((size_t)(32 + i) * 16 + c) * 6 + 2 * r;
            acc *= fmaf(urow[i], k[0], k[1]);
        }
        U1[(size_t)ba * 48 + rc] = acc;
    } else {
#pragma unroll 8
        for (int i = 0; i < 64; ++i) {
            const float* k = dke2 + ((size_t)(96 + i) * 16 + c) * 6 + 2 * r;
            acc *= fmaf(urow[i], k[0], k[1]);
        }
        U2[(size_t)ba * 48 + rc] = acc;
    }
}

// ---------------- Kernel 4: combine + binary/unary reductions ----------------
// grid: 384 blocks (b,a). block: 64 threads = pl(4) x c(16); thread = 6 perms j=pl+4m.
__global__ __launch_bounds__(64) void combine2_kernel(const float* __restrict__ U1,
                                                      const float* __restrict__ U2,
                                                      const float* __restrict__ t3,
                                                      const float* __restrict__ t4,
                                                      const float* __restrict__ orK,
                                                      const float* __restrict__ temp,
                                                      float* __restrict__ out,
                                                      float* __restrict__ ws0) {
    __shared__ float u2sh[24 * 48];   // 4.6 KB: U2 for all bb of this b

    const int tid = threadIdx.x;
    const int b = blockIdx.x / 24;
    const int a = blockIdx.x % 24;
    const int pl = tid >> 4;
    const int c = tid & 15;

    for (int idx = tid; idx < 1152; idx += 64)
        u2sh[idx] = U2[(size_t)b * 1152 + idx];
    __syncthreads();

    float u1r[3];
#pragma unroll
    for (int r = 0; r < 3; ++r)
        u1r[r] = U1[(size_t)(b * 24 + a) * 48 + r * 16 + c];

    const float T = temp[0];
    const float ok2 = sigm(orK[32 + c] / T);
    float au1 = 1.0f, au0 = 1.0f;

#pragma unroll
    for (int m = 0; m < 6; ++m) {
        int j = pl + 4 * m;
        int jv = j < 23 ? j : 22;           // pad lane recomputes j=22, outputs masked
        int bb = jv + (jv >= a ? 1 : 0);
        int aadj = (a > bb) ? (a - 1) : a;
        size_t base3 = (((size_t)b * 24 + a) * 23 + jv) * 48 + c;
        size_t base4 = (((size_t)b * 24 + bb) * 23 + aadj) * 48 + c;
        float c0 = u1r[0] * u2sh[bb * 48 + c]      * t3[base3]      * t4[base4];
        float c1 = u1r[1] * u2sh[bb * 48 + 16 + c] * t3[base3 + 16] * t4[base4 + 16];
        float c2 = u1r[2] * u2sh[bb * 48 + 32 + c] * t3[base3 + 32] * t4[base4 + 32];
        float w = 1.0f - c2 * ok2;
#pragma unroll
        for (int off = 1; off < 16; off <<= 1) w *= __shfl_xor(w, off, 16);
        if (c == 0 && j < 23) out[400 + ((size_t)b * 24 + a) * 23 + j] = 1.0f - w;
        if (j < 23) {
            au1 *= (1.0f - c1);
            au0 *= (1.0f - c0);
        }
    }

    // fold across pl (tid bits 4,5)
    au1 *= __shfl_xor(au1, 16, 64);  au1 *= __shfl_xor(au1, 32, 64);
    au0 *= __shfl_xor(au0, 16, 64);  au0 *= __shfl_xor(au0, 32, 64);

    // unary out
    {
        float ok1 = sigm(orK[16 + c] / T);
        float w = 1.0f - (1.0f - au1) * ok1;
#pragma unroll
        for (int off = 1; off < 16; off <<= 1) w *= __shfl_xor(w, off, 16);
        if (tid == 0) out[16 + (size_t)b * 24 + a] = 1.0f - w;
    }
    // nullary partial
    if (pl == 0) ws0[((size_t)b * 24 + a) * 16 + c] = au0;
}

// ---------------- Kernel 5: nullary finish ----------------
__global__ __launch_bounds__(256) void final_kernel(const float* __restrict__ ws0,
                                                    const float* __restrict__ orK,
                                                    const float* __restrict__ temp,
                                                    float* __restrict__ out) {
    int tid = threadIdx.x;       // 256 = 16 b * 16 c
    int b = tid >> 4, c = tid & 15;
    float p = 1.0f;
#pragma unroll
    for (int a = 0; a < 24; ++a) p *= ws0[((size_t)b * 24 + a) * 16 + c];
    float T = temp[0];
    float ok0 = sigm(orK[c] / T);
    float w = 1.0f - (1.0f - p) * ok0;
#pragma unroll
    for (int off = 1; off < 16; off <<= 1) w *= __shfl_xor(w, off, 16);
    if (c == 0) out[b] = 1.0f - w;
}

extern "C" void kernel_launch(void* const* d_in, const int* in_sizes, int n_in,
                              void* d_out, int out_size, void* d_ws, size_t ws_size,
                              hipStream_t stream) {
    const float* nullary = (const float*)d_in[0];   // (16,32)
    const float* unary   = (const float*)d_in[1];   // (16,24,64)
    const float* binary  = (const float*)d_in[2];   // (16,24,23,64)
    const float* ak      = (const float*)d_in[3];   // (3,16,288,3)
    const float* orK     = (const float*)d_in[4];   // (3,16)
    const float* temp    = (const float*)d_in[5];   // scalar

    float* out  = (float*)d_out;                    // 16 + 384 + 8832 floats
    float* dke2 = (float*)d_ws;                     // 27648 floats
    float* t3   = dke2 + 27648;                     // 423936
    float* t4   = t3 + 423936;                      // 423936
    float* U1   = t4 + 423936;                      // 18432
    float* U2   = U1 + 18432;                       // 18432
    float* ws0  = U2 + 18432;                       // 6144

    prep_kernel<<<54, 256, 0, stream>>>(ak, temp, dke2);
    segprod_kernel<<<16 * 24, 256, 0, stream>>>(binary, dke2, t3, t4);
    useg_kernel<<<384, 128, 0, stream>>>(nullary, unary, dke2, U1, U2);
    combine2_kernel<<<384, 64, 0, stream>>>(U1, U2, t3, t4, orK, temp, out, ws0);
    final_kernel<<<1, 256, 0, stream>>>(ws0, orK, temp, out);
}